// Round 1
// baseline (5815.372 us; speedup 1.0000x reference)
//
#include <hip/hip_runtime.h>
#include <hip/hip_bf16.h>

// Problem constants (match reference setup_inputs)
#define T_TOK 8192   // B*S tokens
#define HID   2048   // hidden
#define NE    64     // experts
#define NI    768    // moe intermediate
#define TOPK  8

#define LDT 40       // padded LDS row stride in bf16 (32 data + 8 pad) -> 80B, 16B-aligned, 2-way-only bank aliasing

typedef __attribute__((ext_vector_type(8))) short bf16x8;
typedef __attribute__((ext_vector_type(4))) float f32x4;

__device__ __forceinline__ ushort f2bf(float f) {
  // round-to-nearest-even fp32 -> bf16
  unsigned u = __float_as_uint(f);
  u += 0x7FFFu + ((u >> 16) & 1u);
  return (ushort)(u >> 16);
}

// ---------------------------------------------------------------------------
// K0: zero the out accumulator (harness poisons 0xAA) + expert counts
__global__ __launch_bounds__(256) void zero_kernel(float4* __restrict__ out4,
                                                   int* __restrict__ counts) {
  const size_t n = (size_t)T_TOK * HID / 4;
  size_t i = (size_t)blockIdx.x * 256 + threadIdx.x;
  const size_t stride = (size_t)gridDim.x * 256;
  float4 z = {0.f, 0.f, 0.f, 0.f};
  for (; i < n; i += stride) out4[i] = z;
  if (blockIdx.x == 0 && threadIdx.x < NE) counts[threadIdx.x] = 0;
}

// ---------------------------------------------------------------------------
// K1: router. One block per token. fp32-exact logits (written to d_out),
// x -> bf16 copy, top-8 + renormalize, scatter to per-expert lists.
__global__ __launch_bounds__(256) void router_kernel(
    const float* __restrict__ x, const float* __restrict__ gw,
    float* __restrict__ logits_out, ushort* __restrict__ xb,
    int* __restrict__ counts, int* __restrict__ etok, float* __restrict__ ew) {
  __shared__ float xs[HID];
  __shared__ float lg[NE];
  const int t = blockIdx.x;
  const int tid = threadIdx.x;
  const float* xp = x + (size_t)t * HID;
  for (int i = tid; i < HID; i += 256) {
    float v = xp[i];
    xs[i] = v;
    xb[(size_t)t * HID + i] = f2bf(v);
  }
  __syncthreads();
  const int wid = tid >> 6, lane = tid & 63;
  // wave w computes experts [16w, 16w+16): coalesced weight-row reads + shuffle reduce
  for (int j = 0; j < 16; ++j) {
    int e = wid * 16 + j;
    const float* wp = gw + (size_t)e * HID;
    float p = 0.f;
    #pragma unroll 8
    for (int c = 0; c < HID / 64; ++c)
      p += xs[lane + 64 * c] * wp[lane + 64 * c];
    for (int off = 32; off > 0; off >>= 1)
      p += __shfl_down(p, off, 64);
    if (lane == 0) {
      lg[e] = p;
      logits_out[(size_t)t * NE + e] = p;
    }
  }
  __syncthreads();
  if (tid == 0) {
    // serial top-8 over 64 (ties -> lowest index, matching lax.top_k)
    bool sel[NE];
    for (int e = 0; e < NE; ++e) sel[e] = false;
    int bi[TOPK]; float bv[TOPK];
    for (int k = 0; k < TOPK; ++k) {
      float best = -1e30f; int b = 0;
      for (int e = 0; e < NE; ++e)
        if (!sel[e] && lg[e] > best) { best = lg[e]; b = e; }
      sel[b] = true; bi[k] = b; bv[k] = best;
    }
    // renormalized top-k softmax: full denominator cancels
    float m0 = bv[0], s = 0.f, ev[TOPK];
    for (int k = 0; k < TOPK; ++k) { ev[k] = expf(bv[k] - m0); s += ev[k]; }
    float inv = 1.f / s;
    for (int k = 0; k < TOPK; ++k) {
      int e = bi[k];
      int pos = atomicAdd(&counts[e], 1);
      etok[e * T_TOK + pos] = t;
      ew[e * T_TOK + pos] = ev[k] * inv;
    }
  }
}

// ---------------------------------------------------------------------------
// K2: exclusive scan of counts (64 entries, single thread — trivial)
__global__ void scan_kernel(const int* __restrict__ counts, int* __restrict__ offs) {
  if (threadIdx.x == 0 && blockIdx.x == 0) {
    int a = 0;
    for (int e = 0; e < NE; ++e) { offs[e] = a; a += counts[e]; }
  }
}

// ---------------------------------------------------------------------------
// K3: gate+up GEMM + SwiGLU. Block = (expert z, token-tile x [128], i-tile y [64]).
// B-tile rows 0..63 = gate rows i0..i0+63, rows 64..127 = up rows i0..i0+63.
// acc: wave handles 32 token-rows (2 m-tiles) x 8 n-tiles of 16.
__global__ __launch_bounds__(256) void gateup_kernel(
    const float* __restrict__ gp, const float* __restrict__ up,
    const ushort* __restrict__ xb, const int* __restrict__ counts,
    const int* __restrict__ offs, const int* __restrict__ etok,
    ushort* __restrict__ hbuf) {
  const int e = blockIdx.z;
  const int count = counts[e];
  const int m0 = blockIdx.x * 128;
  if (m0 >= count) return;
  const int i0 = blockIdx.y * 64;
  const int tid = threadIdx.x;

  __shared__ ushort As[128 * LDT];
  __shared__ ushort Bs[128 * LDT];
  __shared__ int toks[128];

  if (tid < 128) {
    int pos = m0 + tid;
    if (pos > count - 1) pos = count - 1;  // clamp; epilogue masks
    toks[tid] = etok[e * T_TOK + pos];
  }
  __syncthreads();

  const int wid = tid >> 6, lane = tid & 63, q = lane >> 4, ln = lane & 15;
  f32x4 acc[2][8];
  #pragma unroll
  for (int a = 0; a < 2; ++a)
    #pragma unroll
    for (int b = 0; b < 8; ++b) acc[a][b] = (f32x4){0.f, 0.f, 0.f, 0.f};

  for (int kc = 0; kc < HID / 32; ++kc) {
    // stage A: 128x32 bf16 from xb (16B vector loads)
    #pragma unroll
    for (int it = 0; it < 2; ++it) {
      int c = tid + 256 * it;      // 512 chunks of 8 bf16
      int row = c >> 2, ko = (c & 3) * 8;
      const ushort* src = xb + (size_t)toks[row] * HID + kc * 32 + ko;
      *(uint4*)&As[row * LDT + ko] = *(const uint4*)src;
    }
    // stage B: 128x32 fp32 -> bf16 (gate rows then up rows)
    #pragma unroll
    for (int it = 0; it < 4; ++it) {
      int c = tid + 256 * it;      // 1024 chunks of 4 floats
      int row = c >> 3, ko = (c & 7) * 4;
      const float* src = (row < 64)
          ? gp + ((size_t)e * NI + i0 + row) * HID + kc * 32 + ko
          : up + ((size_t)e * NI + i0 + (row - 64)) * HID + kc * 32 + ko;
      float4 v = *(const float4*)src;
      ushort4 o = {f2bf(v.x), f2bf(v.y), f2bf(v.z), f2bf(v.w)};
      *(ushort4*)&Bs[row * LDT + ko] = o;
    }
    __syncthreads();
    bf16x8 a0 = *(const bf16x8*)&As[(wid * 32 + ln) * LDT + q * 8];
    bf16x8 a1 = *(const bf16x8*)&As[(wid * 32 + 16 + ln) * LDT + q * 8];
    #pragma unroll
    for (int nt = 0; nt < 8; ++nt) {
      bf16x8 b = *(const bf16x8*)&Bs[(nt * 16 + ln) * LDT + q * 8];
      acc[0][nt] = __builtin_amdgcn_mfma_f32_16x16x32_bf16(a0, b, acc[0][nt], 0, 0, 0);
      acc[1][nt] = __builtin_amdgcn_mfma_f32_16x16x32_bf16(a1, b, acc[1][nt], 0, 0, 0);
    }
    __syncthreads();
  }

  const int off_e = offs[e];
  #pragma unroll
  for (int mtl = 0; mtl < 2; ++mtl) {
    #pragma unroll
    for (int nt = 0; nt < 4; ++nt) {
      f32x4 g = acc[mtl][nt], u = acc[mtl][nt + 4];
      #pragma unroll
      for (int r = 0; r < 4; ++r) {
        int row = wid * 32 + mtl * 16 + q * 4 + r;  // C/D: row=q*4+reg, col=ln
        if (m0 + row < count) {
          float gv = g[r], uv = u[r];
          float hv = gv / (1.f + __expf(-gv)) * uv;  // silu(g)*u
          hbuf[(size_t)(off_e + m0 + row) * NI + i0 + nt * 16 + ln] = f2bf(hv);
        }
      }
    }
  }
}

// ---------------------------------------------------------------------------
// K4: down GEMM + weighted atomic accumulate into out.
// Block = (expert z, token-tile x [128], H-tile y [128]).
__global__ __launch_bounds__(256) void down_kernel(
    const float* __restrict__ dp, const ushort* __restrict__ hbuf,
    const int* __restrict__ counts, const int* __restrict__ offs,
    const int* __restrict__ etok, const float* __restrict__ ew,
    float* __restrict__ out) {
  const int e = blockIdx.z;
  const int count = counts[e];
  const int m0 = blockIdx.x * 128;
  if (m0 >= count) return;
  const int n0 = blockIdx.y * 128;
  const int tid = threadIdx.x;

  __shared__ ushort As[128 * LDT];
  __shared__ ushort Bs[128 * LDT];
  __shared__ int toks[128];
  __shared__ float wts[128];

  const int off_e = offs[e];
  if (tid < 128) {
    int pos = m0 + tid;
    if (pos > count - 1) pos = count - 1;
    toks[tid] = etok[e * T_TOK + pos];
    wts[tid] = ew[e * T_TOK + pos];
  }
  __syncthreads();

  const int wid = tid >> 6, lane = tid & 63, q = lane >> 4, ln = lane & 15;
  f32x4 acc[2][8];
  #pragma unroll
  for (int a = 0; a < 2; ++a)
    #pragma unroll
    for (int b = 0; b < 8; ++b) acc[a][b] = (f32x4){0.f, 0.f, 0.f, 0.f};

  for (int kc = 0; kc < NI / 32; ++kc) {
    #pragma unroll
    for (int it = 0; it < 2; ++it) {
      int c = tid + 256 * it;
      int row = c >> 2, ko = (c & 3) * 8;
      int pos = m0 + row;
      if (pos > count - 1) pos = count - 1;  // keep hbuf reads in-bounds
      const ushort* src = hbuf + (size_t)(off_e + pos) * NI + kc * 32 + ko;
      *(uint4*)&As[row * LDT + ko] = *(const uint4*)src;
    }
    #pragma unroll
    for (int it = 0; it < 4; ++it) {
      int c = tid + 256 * it;
      int row = c >> 3, ko = (c & 7) * 4;
      const float* src = dp + ((size_t)e * HID + n0 + row) * NI + kc * 32 + ko;
      float4 v = *(const float4*)src;
      ushort4 o = {f2bf(v.x), f2bf(v.y), f2bf(v.z), f2bf(v.w)};
      *(ushort4*)&Bs[row * LDT + ko] = o;
    }
    __syncthreads();
    bf16x8 a0 = *(const bf16x8*)&As[(wid * 32 + ln) * LDT + q * 8];
    bf16x8 a1 = *(const bf16x8*)&As[(wid * 32 + 16 + ln) * LDT + q * 8];
    #pragma unroll
    for (int nt = 0; nt < 8; ++nt) {
      bf16x8 b = *(const bf16x8*)&Bs[(nt * 16 + ln) * LDT + q * 8];
      acc[0][nt] = __builtin_amdgcn_mfma_f32_16x16x32_bf16(a0, b, acc[0][nt], 0, 0, 0);
      acc[1][nt] = __builtin_amdgcn_mfma_f32_16x16x32_bf16(a1, b, acc[1][nt], 0, 0, 0);
    }
    __syncthreads();
  }

  #pragma unroll
  for (int mtl = 0; mtl < 2; ++mtl) {
    #pragma unroll
    for (int nt = 0; nt < 8; ++nt) {
      f32x4 a = acc[mtl][nt];
      #pragma unroll
      for (int r = 0; r < 4; ++r) {
        int row = wid * 32 + mtl * 16 + q * 4 + r;
        if (m0 + row < count) {
          float v = a[r] * wts[row];
          unsafeAtomicAdd(&out[(size_t)toks[row] * HID + n0 + nt * 16 + ln], v);
        }
      }
    }
  }
}

// ---------------------------------------------------------------------------
extern "C" void kernel_launch(void* const* d_in, const int* in_sizes, int n_in,
                              void* d_out, int out_size, void* d_ws, size_t ws_size,
                              hipStream_t stream) {
  const float* x  = (const float*)d_in[0];   // [T, H]
  const float* gw = (const float*)d_in[1];   // [E, H]
  const float* gp = (const float*)d_in[2];   // [E, I, H]
  const float* up = (const float*)d_in[3];   // [E, I, H]
  const float* dp = (const float*)d_in[4];   // [E, H, I]
  float* out = (float*)d_out;                            // [T*H] out, then [T*E] logits
  float* logits = out + (size_t)T_TOK * HID;

  // workspace layout (~138.4 MB total)
  char* ws = (char*)d_ws;
  int*    counts = (int*)ws;                                         // 256 B
  int*    offs   = (int*)(ws + 256);                                 // 260 B
  int*    etok   = (int*)(ws + 1024);                                // 2 MB
  float*  ew     = (float*)(ws + 1024 + (size_t)NE * T_TOK * 4);     // 2 MB
  ushort* xb     = (ushort*)(ws + 1024 + 2 * (size_t)NE * T_TOK * 4);// 33.6 MB
  ushort* hbuf   = xb + (size_t)T_TOK * HID;                         // 100.7 MB

  zero_kernel<<<4096, 256, 0, stream>>>((float4*)out, counts);
  router_kernel<<<T_TOK, 256, 0, stream>>>(x, gw, logits, xb, counts, etok, ew);
  scan_kernel<<<1, 64, 0, stream>>>(counts, offs);
  gateup_kernel<<<dim3(64, 12, NE), 256, 0, stream>>>(gp, up, xb, counts, offs, etok, hbuf);
  down_kernel<<<dim3(64, 16, NE), 256, 0, stream>>>(dp, hbuf, counts, offs, etok, ew, out);
}